// Round 4
// baseline (1038.648 us; speedup 1.0000x reference)
//
#include <hip/hip_runtime.h>
#include <hip/hip_fp16.h>

// ForwardWarp via two-phase binning:
//   Pass A: per source pixel, emit 16B record(s) into per-output-tile bins.
//           Block-aggregated slot allocation (LDS count table + one global
//           atomicAdd per distinct bin per block). Overflow records append
//           to a global overflow list (pass C drains it after the flush).
//   Pass B: per tile, batched record loads (4-deep MLP), LDS accumulate,
//           plain-store flush (bins tile the output exactly once).
//   Pass C: drains the overflow list with global atomics (normally empty).
// img: (8,3,1024,1024) fp32; flo: (8,2,1024,1024) fp32
// d_out = [imgw (8,3,1024,1024) | onew (8,3,1024,1024)] fp32.

#define NN 8
#define CC 3
#define HH 1024
#define WW 1024
#define HW (HH * WW)
#define NCHW (NN * CC * HW)
#define NBINS (NN * 32 * 32)          // 8192 tiles of 32x32
#define CUR_STRIDE 32                 // 1 counter per 128B line (kills false sharing)
#define OC_OFF (NBINS * CUR_STRIDE)   // overflow-list counter slot
#define CUR_BYTES ((NBINS * CUR_STRIDE + 32) * 4)
#define RB 4                          // record-load batch depth in pass B

__device__ __forceinline__ unsigned pack2h(float a, float b) {
    __half2 h = __floats2half2_rn(a, b);
    return *reinterpret_cast<unsigned*>(&h);
}
__device__ __forceinline__ float2 unpack2h(unsigned u) {
    __half2 h = *reinterpret_cast<__half2*>(&u);
    return __half22float2(h);
}

// direct global-atomic fallback for one (pixel, tile) when even the overflow
// list is full (requires out to be pre-zeroed; flush switches to += for the
// affected bin via the dirty flag)
__device__ void apply_fallback(float* imgw, float* onew, int n, int tr, int tc,
                               int ix, int iy, const float wx[2], const float wy[2],
                               float v0, float v1, float v2) {
#pragma unroll
    for (int dx = 0; dx < 2; ++dx) {
        int r = ix + dx;
        if ((unsigned)r >= (unsigned)HH || (r >> 5) != tr) continue;
#pragma unroll
        for (int dy = 0; dy < 2; ++dy) {
            int c = iy + dy;
            if ((unsigned)c >= (unsigned)WW || (c >> 5) != tc) continue;
            float w = wx[dx] * wy[dy];
            long o = (long)(n * CC) * HW + (long)r * WW + c;
            atomicAdd(&imgw[o], v0 * w);
            atomicAdd(&imgw[o + HW], v1 * w);
            atomicAdd(&imgw[o + 2 * HW], v2 * w);
            atomicAdd(&onew[o], w);
            atomicAdd(&onew[o + HW], w);
            atomicAdd(&onew[o + 2 * HW], w);
        }
    }
}

__global__ __launch_bounds__(256) void fwarp_binA(
    const float* __restrict__ img, const float* __restrict__ flo,
    float* __restrict__ imgw, float* __restrict__ onew,
    unsigned* __restrict__ cur, uint4* __restrict__ recs, int CAP,
    uint4* __restrict__ ov_rec, unsigned* __restrict__ ov_bin, int OCAP)
{
    __shared__ unsigned tbl[1024];    // per-(tr,tc): count, then base

    const int tid = threadIdx.x;
    const int idx = blockIdx.x * 256 + tid;   // over N*H*W
    const int wi = idx & (WW - 1);
    const int hi = (idx >> 10) & (HH - 1);
    const int n  = idx >> 20;                 // uniform per block

#pragma unroll
    for (int i = tid; i < 1024; i += 256) tbl[i] = 0u;

    const long pix = (long)hi * WW + wi;
    const long fb = (long)(n * 2) * HW + pix;
    const float yf = flo[fb];         // column shift
    const float xf = flo[fb + HW];    // row shift

    const float x1 = floorf(xf);
    const float y1 = floorf(yf);
    const float fx = xf - x1;
    const float fy = yf - y1;
    const int ix = (int)x1 + hi;      // target row (corner dx=0)
    const int iy = (int)y1 + wi;      // target col (corner dy=0)

    float wx[2], wy[2];
    wx[0] = __expf(-fx * fx);
    wx[1] = __expf(-(fx - 1.0f) * (fx - 1.0f));
    wy[0] = __expf(-fy * fy);
    wy[1] = __expf(-(fy - 1.0f) * (fy - 1.0f));

    const long ib = (long)(n * CC) * HW + pix;
    const float v0 = img[ib];
    const float v1 = img[ib + HW];
    const float v2 = img[ib + 2 * HW];

    // unique tile-rows touched by corner rows {ix, ix+1} ∩ [0,1024)
    int trs[2]; int ntr = 0;
    if ((unsigned)ix < (unsigned)HH) trs[ntr++] = ix >> 5;
    if ((unsigned)(ix + 1) < (unsigned)HH) {
        int t = (ix + 1) >> 5;
        if (ntr == 0 || t != trs[0]) trs[ntr++] = t;
    }
    int tcs[2]; int ntc = 0;
    if ((unsigned)iy < (unsigned)WW) tcs[ntc++] = iy >> 5;
    if ((unsigned)(iy + 1) < (unsigned)WW) {
        int t = (iy + 1) >> 5;
        if (ntc == 0 || t != tcs[0]) tcs[ntc++] = t;
    }

    const unsigned uwx = pack2h(wx[0], wx[1]);
    const unsigned uwy = pack2h(wy[0], wy[1]);
    const unsigned uv01 = pack2h(v0, v1);
    const unsigned uv2 = pack2h(v2, 0.0f) & 0xFFFFu;

    // collect this thread's (tile, loc) list: up to 4 records, distinct tiles
    int nrec = 0;
    int tv[4];
    unsigned locv[4];
#pragma unroll
    for (int i = 0; i < 2; ++i) {
        if (i >= ntr) break;
#pragma unroll
        for (int j = 0; j < 2; ++j) {
            if (j >= ntc) break;
            const int tr = trs[i], tc = tcs[j];
            const int lr = ix - (tr << 5);          // [-1..31]
            const int lc = iy - (tc << 5);          // [-1..31]
            tv[nrec] = (tr << 5) + tc;
            locv[nrec] = (unsigned)(lr + 1) | ((unsigned)(lc + 1) << 6);
            ++nrec;
        }
    }

    __syncthreads();   // tbl zeroed

    // phase 1: per-block count + per-record rank via LDS atomics
    unsigned rankv[4];
#pragma unroll
    for (int k = 0; k < 4; ++k)
        if (k < nrec) rankv[k] = atomicAdd(&tbl[tv[k]], 1u);
    __syncthreads();

    // phase 2: reserve global ranges — one atomic per distinct bin, issued
    // concurrently across lanes (4 independent atomics per thread, pipelined)
    unsigned cnts[4];
#pragma unroll
    for (int j = 0; j < 4; ++j) cnts[j] = tbl[tid + j * 256];
#pragma unroll
    for (int j = 0; j < 4; ++j) {
        if (cnts[j] > 0u) {
            const int e = tid + j * 256;
            const int bin = (n << 10) + e;
            tbl[e] = atomicAdd(&cur[(size_t)bin * CUR_STRIDE], cnts[j]);
        }
    }
    __syncthreads();

    // phase 3: store records at base + rank (consecutive per block per bin)
    uint4 rec;
    rec.x = uwx; rec.y = uwy; rec.z = uv01;
#pragma unroll
    for (int k = 0; k < 4; ++k) {
        if (k < nrec) {
            const unsigned slot = tbl[tv[k]] + rankv[k];
            const int bin = (n << 10) + tv[k];
            rec.w = uv2 | (locv[k] << 16);
            if (slot < (unsigned)CAP) {
                recs[(size_t)bin * CAP + slot] = rec;
            } else {
                const unsigned oslot = atomicAdd(&cur[OC_OFF], 1u);
                if ((int)oslot < OCAP) {
                    ov_rec[oslot] = rec;
                    ov_bin[oslot] = (unsigned)bin;
                } else {
                    // overflow list full: direct atomics + mark bin dirty
                    atomicOr(&cur[(size_t)bin * CUR_STRIDE + 1], 1u);
                    apply_fallback(imgw, onew, n, tv[k] >> 5, tv[k] & 31,
                                   ix, iy, wx, wy, v0, v1, v2);
                }
            }
        }
    }
}

__global__ __launch_bounds__(256, 8) void fwarp_binB(
    float* __restrict__ imgw, float* __restrict__ onew,
    const unsigned* __restrict__ cur, const uint4* __restrict__ recs, int CAP)
{
    __shared__ float p0[1024], p1[1024], p2[1024], pw[1024];
    const int bin = blockIdx.x;
    const int tid = threadIdx.x;
    const int n = bin >> 10;
    const int tr = (bin >> 5) & 31;
    const int tc = bin & 31;

#pragma unroll
    for (int i = tid; i < 1024; i += 256) {
        p0[i] = 0.0f; p1[i] = 0.0f; p2[i] = 0.0f; pw[i] = 0.0f;
    }
    __syncthreads();

    const int cnt = min((int)cur[(size_t)bin * CUR_STRIDE], CAP);
    const unsigned dirty = cur[(size_t)bin * CUR_STRIDE + 1];
    const uint4* base = recs + (size_t)bin * CAP;

    // batched record loads: RB independent 16B loads in flight per thread
    for (int i0 = tid; i0 < cnt; i0 += 256 * RB) {
        uint4 r[RB];
        bool m[RB];
#pragma unroll
        for (int b = 0; b < RB; ++b) {
            const int i = i0 + b * 256;
            m[b] = (i < cnt);
            if (m[b]) r[b] = base[i];
        }
#pragma unroll
        for (int b = 0; b < RB; ++b) {
            if (!m[b]) continue;
            const uint4 rec = r[b];
            const float2 wx = unpack2h(rec.x);
            const float2 wy = unpack2h(rec.y);
            const float2 v01 = unpack2h(rec.z);
            const float v2 = unpack2h(rec.w & 0xFFFFu).x;
            const unsigned loc = rec.w >> 16;
            const int lr = (int)(loc & 63u) - 1;        // [-1..31]
            const int lc = (int)(loc >> 6) - 1;
            const float wxv[2] = {wx.x, wx.y};
            const float wyv[2] = {wy.x, wy.y};
#pragma unroll
            for (int dx = 0; dx < 2; ++dx) {
                const int rr = lr + dx;
                if ((unsigned)rr >= 32u) continue;
#pragma unroll
                for (int dy = 0; dy < 2; ++dy) {
                    const int c = lc + dy;
                    if ((unsigned)c >= 32u) continue;
                    const float w = wxv[dx] * wyv[dy];
                    const int cell = (rr << 5) + c;
                    atomicAdd(&p0[cell], v01.x * w);
                    atomicAdd(&p1[cell], v01.y * w);
                    atomicAdd(&p2[cell], v2 * w);
                    atomicAdd(&pw[cell], w);
                }
            }
        }
    }
    __syncthreads();

    // flush: bins tile the output exactly once -> plain stores.
    // (dirty bins — only possible when the overflow list overflowed — keep
    //  the += path on the pre-zeroed output.)
#pragma unroll
    for (int i = tid; i < 1024; i += 256) {
        const int gr = (tr << 5) + (i >> 5);
        const int gc = (tc << 5) + (i & 31);
        const long o = (long)(n * CC) * HW + (long)gr * WW + gc;
        const float w = pw[i];
        if (dirty == 0u) {
            imgw[o]          = p0[i];
            imgw[o + HW]     = p1[i];
            imgw[o + 2 * HW] = p2[i];
            onew[o]          = w;
            onew[o + HW]     = w;
            onew[o + 2 * HW] = w;
        } else {
            imgw[o]          += p0[i];
            imgw[o + HW]     += p1[i];
            imgw[o + 2 * HW] += p2[i];
            onew[o]          += w;
            onew[o + HW]     += w;
            onew[o + 2 * HW] += w;
        }
    }
}

// drains the overflow list (normally empty) after the flush
__global__ __launch_bounds__(256) void fwarp_binC(
    float* __restrict__ imgw, float* __restrict__ onew,
    const unsigned* __restrict__ cur,
    const uint4* __restrict__ ov_rec, const unsigned* __restrict__ ov_bin,
    int OCAP)
{
    const int ocnt = min((int)cur[OC_OFF], OCAP);
    for (int i = blockIdx.x * 256 + threadIdx.x; i < ocnt; i += gridDim.x * 256) {
        const uint4 rec = ov_rec[i];
        const int bin = (int)ov_bin[i];
        const int n = bin >> 10;
        const int tr = (bin >> 5) & 31;
        const int tc = bin & 31;
        const float2 wx = unpack2h(rec.x);
        const float2 wy = unpack2h(rec.y);
        const float2 v01 = unpack2h(rec.z);
        const float v2 = unpack2h(rec.w & 0xFFFFu).x;
        const unsigned loc = rec.w >> 16;
        const int lr = (int)(loc & 63u) - 1;
        const int lc = (int)(loc >> 6) - 1;
        const float wxv[2] = {wx.x, wx.y};
        const float wyv[2] = {wy.x, wy.y};
#pragma unroll
        for (int dx = 0; dx < 2; ++dx) {
            const int r = lr + dx;
            if ((unsigned)r >= 32u) continue;
#pragma unroll
            for (int dy = 0; dy < 2; ++dy) {
                const int c = lc + dy;
                if ((unsigned)c >= 32u) continue;
                const float w = wxv[dx] * wyv[dy];
                const int gr = (tr << 5) + r;
                const int gc = (tc << 5) + c;
                const long o = (long)(n * CC) * HW + (long)gr * WW + gc;
                atomicAdd(&imgw[o], v01.x * w);
                atomicAdd(&imgw[o + HW], v01.y * w);
                atomicAdd(&imgw[o + 2 * HW], v2 * w);
                atomicAdd(&onew[o], w);
                atomicAdd(&onew[o + HW], w);
                atomicAdd(&onew[o + 2 * HW], w);
            }
        }
    }
}

extern "C" void kernel_launch(void* const* d_in, const int* in_sizes, int n_in,
                              void* d_out, int out_size, void* d_ws, size_t ws_size,
                              hipStream_t stream) {
    const float* img = (const float*)d_in[0];
    const float* flo = (const float*)d_in[1];
    float* imgw = (float*)d_out;
    float* onew = imgw + (long)NCHW;

    unsigned* cur = (unsigned*)d_ws;

    size_t avail = ws_size > (size_t)CUR_BYTES ? ws_size - CUR_BYTES : 0;
    // 85% of remaining workspace to bins (CAP ~2x mean load of 1090), 15% to
    // the overflow list
    long cap_l = (long)((avail / 20 * 17) / ((size_t)NBINS * 16));
    int CAP = (int)(cap_l > 2048 ? 2048 : (cap_l < 0 ? 0 : cap_l));
    size_t recs_bytes = (size_t)NBINS * 16 * CAP;
    size_t ov_bytes = avail - recs_bytes;
    long ocap_l = (long)(ov_bytes / 20);
    int OCAP = (int)(ocap_l > (1L << 22) ? (1L << 22) : (ocap_l < 0 ? 0 : ocap_l));

    uint4* recs = (uint4*)((char*)d_ws + CUR_BYTES);
    uint4* ov_rec = (uint4*)((char*)recs + recs_bytes);
    unsigned* ov_bin = (unsigned*)((char*)ov_rec + (size_t)OCAP * 16);

    hipMemsetAsync(d_out, 0, (size_t)out_size * sizeof(float), stream);
    hipMemsetAsync(cur, 0, CUR_BYTES, stream);

    const int total = NN * HH * WW;            // 8388608
    fwarp_binA<<<total / 256, 256, 0, stream>>>(img, flo, imgw, onew, cur, recs,
                                                CAP, ov_rec, ov_bin, OCAP);
    fwarp_binB<<<NBINS, 256, 0, stream>>>(imgw, onew, cur, recs, CAP);
    fwarp_binC<<<64, 256, 0, stream>>>(imgw, onew, cur, ov_rec, ov_bin, OCAP);
}

// Round 5
// 1038.327 us; speedup vs baseline: 1.0003x; 1.0003x over previous
//
#include <hip/hip_runtime.h>
#include <hip/hip_fp16.h>

// ForwardWarp via two-phase binning:
//   Pass A: per source pixel, emit 16B record(s) into per-output-tile bins.
//           Block-aggregated slot allocation (LDS count table + one global
//           atomicAdd per distinct bin per block). Overflow records append
//           to a global overflow list (pass C drains it after the flush).
//   Pass B: per tile, batched record loads, LDS accumulate via NATIVE fp32
//           LDS atomics (unsafeAtomicAdd -> ds_add_f32; plain atomicAdd
//           lowers to a CAS retry loop = ~200cy dependent round-trip each),
//           plain-store flush (bins tile the output exactly once).
//   Pass C: drains the overflow list with global atomics (normally empty).
// img: (8,3,1024,1024) fp32; flo: (8,2,1024,1024) fp32
// d_out = [imgw (8,3,1024,1024) | onew (8,3,1024,1024)] fp32.

#define NN 8
#define CC 3
#define HH 1024
#define WW 1024
#define HW (HH * WW)
#define NCHW (NN * CC * HW)
#define NBINS (NN * 32 * 32)          // 8192 tiles of 32x32
#define CUR_STRIDE 32                 // 1 counter per 128B line (kills false sharing)
#define OC_OFF (NBINS * CUR_STRIDE)   // overflow-list counter slot
#define CUR_BYTES ((NBINS * CUR_STRIDE + 32) * 4)
#define RB 4                          // record-load batch depth in pass B

__device__ __forceinline__ unsigned pack2h(float a, float b) {
    __half2 h = __floats2half2_rn(a, b);
    return *reinterpret_cast<unsigned*>(&h);
}
__device__ __forceinline__ float2 unpack2h(unsigned u) {
    __half2 h = *reinterpret_cast<__half2*>(&u);
    return __half22float2(h);
}

// native fp32 atomic add (ds_add_f32 / global_atomic_add_f32) — no CAS loop
__device__ __forceinline__ void fadd_native(float* p, float v) {
    unsafeAtomicAdd(p, v);
}

// direct global-atomic fallback for one (pixel, tile) when even the overflow
// list is full (requires out to be pre-zeroed; flush switches to += for the
// affected bin via the dirty flag)
__device__ void apply_fallback(float* imgw, float* onew, int n, int tr, int tc,
                               int ix, int iy, const float wx[2], const float wy[2],
                               float v0, float v1, float v2) {
#pragma unroll
    for (int dx = 0; dx < 2; ++dx) {
        int r = ix + dx;
        if ((unsigned)r >= (unsigned)HH || (r >> 5) != tr) continue;
#pragma unroll
        for (int dy = 0; dy < 2; ++dy) {
            int c = iy + dy;
            if ((unsigned)c >= (unsigned)WW || (c >> 5) != tc) continue;
            float w = wx[dx] * wy[dy];
            long o = (long)(n * CC) * HW + (long)r * WW + c;
            fadd_native(&imgw[o], v0 * w);
            fadd_native(&imgw[o + HW], v1 * w);
            fadd_native(&imgw[o + 2 * HW], v2 * w);
            fadd_native(&onew[o], w);
            fadd_native(&onew[o + HW], w);
            fadd_native(&onew[o + 2 * HW], w);
        }
    }
}

__global__ __launch_bounds__(256) void fwarp_binA(
    const float* __restrict__ img, const float* __restrict__ flo,
    float* __restrict__ imgw, float* __restrict__ onew,
    unsigned* __restrict__ cur, uint4* __restrict__ recs, int CAP,
    uint4* __restrict__ ov_rec, unsigned* __restrict__ ov_bin, int OCAP)
{
    __shared__ unsigned tbl[1024];    // per-(tr,tc): count, then base

    const int tid = threadIdx.x;
    const int idx = blockIdx.x * 256 + tid;   // over N*H*W
    const int wi = idx & (WW - 1);
    const int hi = (idx >> 10) & (HH - 1);
    const int n  = idx >> 20;                 // uniform per block

#pragma unroll
    for (int i = tid; i < 1024; i += 256) tbl[i] = 0u;

    const long pix = (long)hi * WW + wi;
    const long fb = (long)(n * 2) * HW + pix;
    const float yf = flo[fb];         // column shift
    const float xf = flo[fb + HW];    // row shift

    const float x1 = floorf(xf);
    const float y1 = floorf(yf);
    const float fx = xf - x1;
    const float fy = yf - y1;
    const int ix = (int)x1 + hi;      // target row (corner dx=0)
    const int iy = (int)y1 + wi;      // target col (corner dy=0)

    float wx[2], wy[2];
    wx[0] = __expf(-fx * fx);
    wx[1] = __expf(-(fx - 1.0f) * (fx - 1.0f));
    wy[0] = __expf(-fy * fy);
    wy[1] = __expf(-(fy - 1.0f) * (fy - 1.0f));

    const long ib = (long)(n * CC) * HW + pix;
    const float v0 = img[ib];
    const float v1 = img[ib + HW];
    const float v2 = img[ib + 2 * HW];

    // unique tile-rows touched by corner rows {ix, ix+1} ∩ [0,1024)
    int trs[2]; int ntr = 0;
    if ((unsigned)ix < (unsigned)HH) trs[ntr++] = ix >> 5;
    if ((unsigned)(ix + 1) < (unsigned)HH) {
        int t = (ix + 1) >> 5;
        if (ntr == 0 || t != trs[0]) trs[ntr++] = t;
    }
    int tcs[2]; int ntc = 0;
    if ((unsigned)iy < (unsigned)WW) tcs[ntc++] = iy >> 5;
    if ((unsigned)(iy + 1) < (unsigned)WW) {
        int t = (iy + 1) >> 5;
        if (ntc == 0 || t != tcs[0]) tcs[ntc++] = t;
    }

    const unsigned uwx = pack2h(wx[0], wx[1]);
    const unsigned uwy = pack2h(wy[0], wy[1]);
    const unsigned uv01 = pack2h(v0, v1);
    const unsigned uv2 = pack2h(v2, 0.0f) & 0xFFFFu;

    // collect this thread's (tile, loc) list: up to 4 records, distinct tiles
    int nrec = 0;
    int tv[4];
    unsigned locv[4];
#pragma unroll
    for (int i = 0; i < 2; ++i) {
        if (i >= ntr) break;
#pragma unroll
        for (int j = 0; j < 2; ++j) {
            if (j >= ntc) break;
            const int tr = trs[i], tc = tcs[j];
            const int lr = ix - (tr << 5);          // [-1..31]
            const int lc = iy - (tc << 5);          // [-1..31]
            tv[nrec] = (tr << 5) + tc;
            locv[nrec] = (unsigned)(lr + 1) | ((unsigned)(lc + 1) << 6);
            ++nrec;
        }
    }

    __syncthreads();   // tbl zeroed

    // phase 1: per-block count + per-record rank via LDS atomics
    unsigned rankv[4];
#pragma unroll
    for (int k = 0; k < 4; ++k)
        if (k < nrec) rankv[k] = atomicAdd(&tbl[tv[k]], 1u);
    __syncthreads();

    // phase 2: reserve global ranges — one atomic per distinct bin, issued
    // concurrently across lanes (4 independent atomics per thread, pipelined)
    unsigned cnts[4];
#pragma unroll
    for (int j = 0; j < 4; ++j) cnts[j] = tbl[tid + j * 256];
#pragma unroll
    for (int j = 0; j < 4; ++j) {
        if (cnts[j] > 0u) {
            const int e = tid + j * 256;
            const int bin = (n << 10) + e;
            tbl[e] = atomicAdd(&cur[(size_t)bin * CUR_STRIDE], cnts[j]);
        }
    }
    __syncthreads();

    // phase 3: store records at base + rank (consecutive per block per bin)
    uint4 rec;
    rec.x = uwx; rec.y = uwy; rec.z = uv01;
#pragma unroll
    for (int k = 0; k < 4; ++k) {
        if (k < nrec) {
            const unsigned slot = tbl[tv[k]] + rankv[k];
            const int bin = (n << 10) + tv[k];
            rec.w = uv2 | (locv[k] << 16);
            if (slot < (unsigned)CAP) {
                recs[(size_t)bin * CAP + slot] = rec;
            } else {
                const unsigned oslot = atomicAdd(&cur[OC_OFF], 1u);
                if ((int)oslot < OCAP) {
                    ov_rec[oslot] = rec;
                    ov_bin[oslot] = (unsigned)bin;
                } else {
                    // overflow list full: direct atomics + mark bin dirty
                    atomicOr(&cur[(size_t)bin * CUR_STRIDE + 1], 1u);
                    apply_fallback(imgw, onew, n, tv[k] >> 5, tv[k] & 31,
                                   ix, iy, wx, wy, v0, v1, v2);
                }
            }
        }
    }
}

__global__ __launch_bounds__(256, 8) void fwarp_binB(
    float* __restrict__ imgw, float* __restrict__ onew,
    const unsigned* __restrict__ cur, const uint4* __restrict__ recs, int CAP)
{
    __shared__ float p0[1024], p1[1024], p2[1024], pw[1024];
    const int bin = blockIdx.x;
    const int tid = threadIdx.x;
    const int n = bin >> 10;
    const int tr = (bin >> 5) & 31;
    const int tc = bin & 31;

#pragma unroll
    for (int i = tid; i < 1024; i += 256) {
        p0[i] = 0.0f; p1[i] = 0.0f; p2[i] = 0.0f; pw[i] = 0.0f;
    }
    __syncthreads();

    const int cnt = min((int)cur[(size_t)bin * CUR_STRIDE], CAP);
    const unsigned dirty = cur[(size_t)bin * CUR_STRIDE + 1];
    const uint4* base = recs + (size_t)bin * CAP;

    // batched record loads: RB independent 16B loads in flight per thread
    for (int i0 = tid; i0 < cnt; i0 += 256 * RB) {
        uint4 r[RB];
        bool m[RB];
#pragma unroll
        for (int b = 0; b < RB; ++b) {
            const int i = i0 + b * 256;
            m[b] = (i < cnt);
            if (m[b]) r[b] = base[i];
        }
#pragma unroll
        for (int b = 0; b < RB; ++b) {
            if (!m[b]) continue;
            const uint4 rec = r[b];
            const float2 wx = unpack2h(rec.x);
            const float2 wy = unpack2h(rec.y);
            const float2 v01 = unpack2h(rec.z);
            const float v2 = unpack2h(rec.w & 0xFFFFu).x;
            const unsigned loc = rec.w >> 16;
            const int lr = (int)(loc & 63u) - 1;        // [-1..31]
            const int lc = (int)(loc >> 6) - 1;
            const float wxv[2] = {wx.x, wx.y};
            const float wyv[2] = {wy.x, wy.y};
#pragma unroll
            for (int dx = 0; dx < 2; ++dx) {
                const int rr = lr + dx;
                if ((unsigned)rr >= 32u) continue;
#pragma unroll
                for (int dy = 0; dy < 2; ++dy) {
                    const int c = lc + dy;
                    if ((unsigned)c >= 32u) continue;
                    const float w = wxv[dx] * wyv[dy];
                    const int cell = (rr << 5) + c;
                    fadd_native(&p0[cell], v01.x * w);
                    fadd_native(&p1[cell], v01.y * w);
                    fadd_native(&p2[cell], v2 * w);
                    fadd_native(&pw[cell], w);
                }
            }
        }
    }
    __syncthreads();

    // flush: bins tile the output exactly once -> plain stores.
    // (dirty bins — only possible when the overflow list overflowed — keep
    //  the += path on the pre-zeroed output.)
#pragma unroll
    for (int i = tid; i < 1024; i += 256) {
        const int gr = (tr << 5) + (i >> 5);
        const int gc = (tc << 5) + (i & 31);
        const long o = (long)(n * CC) * HW + (long)gr * WW + gc;
        const float w = pw[i];
        if (dirty == 0u) {
            imgw[o]          = p0[i];
            imgw[o + HW]     = p1[i];
            imgw[o + 2 * HW] = p2[i];
            onew[o]          = w;
            onew[o + HW]     = w;
            onew[o + 2 * HW] = w;
        } else {
            imgw[o]          += p0[i];
            imgw[o + HW]     += p1[i];
            imgw[o + 2 * HW] += p2[i];
            onew[o]          += w;
            onew[o + HW]     += w;
            onew[o + 2 * HW] += w;
        }
    }
}

// drains the overflow list (normally empty) after the flush
__global__ __launch_bounds__(256) void fwarp_binC(
    float* __restrict__ imgw, float* __restrict__ onew,
    const unsigned* __restrict__ cur,
    const uint4* __restrict__ ov_rec, const unsigned* __restrict__ ov_bin,
    int OCAP)
{
    const int ocnt = min((int)cur[OC_OFF], OCAP);
    for (int i = blockIdx.x * 256 + threadIdx.x; i < ocnt; i += gridDim.x * 256) {
        const uint4 rec = ov_rec[i];
        const int bin = (int)ov_bin[i];
        const int n = bin >> 10;
        const int tr = (bin >> 5) & 31;
        const int tc = bin & 31;
        const float2 wx = unpack2h(rec.x);
        const float2 wy = unpack2h(rec.y);
        const float2 v01 = unpack2h(rec.z);
        const float v2 = unpack2h(rec.w & 0xFFFFu).x;
        const unsigned loc = rec.w >> 16;
        const int lr = (int)(loc & 63u) - 1;
        const int lc = (int)(loc >> 6) - 1;
        const float wxv[2] = {wx.x, wx.y};
        const float wyv[2] = {wy.x, wy.y};
#pragma unroll
        for (int dx = 0; dx < 2; ++dx) {
            const int r = lr + dx;
            if ((unsigned)r >= 32u) continue;
#pragma unroll
            for (int dy = 0; dy < 2; ++dy) {
                const int c = lc + dy;
                if ((unsigned)c >= 32u) continue;
                const float w = wxv[dx] * wyv[dy];
                const int gr = (tr << 5) + r;
                const int gc = (tc << 5) + c;
                const long o = (long)(n * CC) * HW + (long)gr * WW + gc;
                fadd_native(&imgw[o], v01.x * w);
                fadd_native(&imgw[o + HW], v01.y * w);
                fadd_native(&imgw[o + 2 * HW], v2 * w);
                fadd_native(&onew[o], w);
                fadd_native(&onew[o + HW], w);
                fadd_native(&onew[o + 2 * HW], w);
            }
        }
    }
}

extern "C" void kernel_launch(void* const* d_in, const int* in_sizes, int n_in,
                              void* d_out, int out_size, void* d_ws, size_t ws_size,
                              hipStream_t stream) {
    const float* img = (const float*)d_in[0];
    const float* flo = (const float*)d_in[1];
    float* imgw = (float*)d_out;
    float* onew = imgw + (long)NCHW;

    unsigned* cur = (unsigned*)d_ws;

    size_t avail = ws_size > (size_t)CUR_BYTES ? ws_size - CUR_BYTES : 0;
    // 85% of remaining workspace to bins (CAP ~2x mean load of 1090), 15% to
    // the overflow list
    long cap_l = (long)((avail / 20 * 17) / ((size_t)NBINS * 16));
    int CAP = (int)(cap_l > 2048 ? 2048 : (cap_l < 0 ? 0 : cap_l));
    size_t recs_bytes = (size_t)NBINS * 16 * CAP;
    size_t ov_bytes = avail - recs_bytes;
    long ocap_l = (long)(ov_bytes / 20);
    int OCAP = (int)(ocap_l > (1L << 22) ? (1L << 22) : (ocap_l < 0 ? 0 : ocap_l));

    uint4* recs = (uint4*)((char*)d_ws + CUR_BYTES);
    uint4* ov_rec = (uint4*)((char*)recs + recs_bytes);
    unsigned* ov_bin = (unsigned*)((char*)ov_rec + (size_t)OCAP * 16);

    hipMemsetAsync(d_out, 0, (size_t)out_size * sizeof(float), stream);
    hipMemsetAsync(cur, 0, CUR_BYTES, stream);

    const int total = NN * HH * WW;            // 8388608
    fwarp_binA<<<total / 256, 256, 0, stream>>>(img, flo, imgw, onew, cur, recs,
                                                CAP, ov_rec, ov_bin, OCAP);
    fwarp_binB<<<NBINS, 256, 0, stream>>>(imgw, onew, cur, recs, CAP);
    fwarp_binC<<<64, 256, 0, stream>>>(imgw, onew, cur, ov_rec, ov_bin, OCAP);
}

// Round 6
// 451.979 us; speedup vs baseline: 2.2980x; 2.2973x over previous
//
#include <hip/hip_runtime.h>
#include <hip/hip_fp16.h>

// ForwardWarp via two-phase binning:
//   Pass A: per source pixel, emit 16B record(s) into per-output-tile bins.
//           Block-aggregated slot allocation (LDS count table + one global
//           atomicAdd per distinct bin per block). Overflow records append
//           to a global overflow list (pass C drains it after the flush).
//   Pass B: per tile, batched record loads, LDS accumulate via PACKED u64
//           fixed-point atomics: 2 planes per ds_add_u64 (8 DS-atomics per
//           record instead of 16 — the LDS atomic pipe at ~3cyc/lane is the
//           measured bottleneck), exact integer sums decoded at the flush.
//   Pass C: drains the overflow list with global atomics (normally empty).
// img: (8,3,1024,1024) fp32; flo: (8,2,1024,1024) fp32
// d_out = [imgw (8,3,1024,1024) | onew (8,3,1024,1024)] fp32.

#define NN 8
#define CC 3
#define HH 1024
#define WW 1024
#define HW (HH * WW)
#define NCHW (NN * CC * HW)
#define NBINS (NN * 32 * 32)          // 8192 tiles of 32x32
#define CUR_STRIDE 32                 // 1 counter per 128B line (kills false sharing)
#define OC_OFF (NBINS * CUR_STRIDE)   // overflow-list counter slot
#define CUR_BYTES ((NBINS * CUR_STRIDE + 32) * 4)
#define RB 4                          // record-load batch depth in pass B

#define FPS 65536.0f                  // fixed-point scale 16.16
#define FPI (1.0f / 65536.0f)

__device__ __forceinline__ unsigned pack2h(float a, float b) {
    __half2 h = __floats2half2_rn(a, b);
    return *reinterpret_cast<unsigned*>(&h);
}
__device__ __forceinline__ float2 unpack2h(unsigned u) {
    __half2 h = *reinterpret_cast<__half2*>(&u);
    return __half22float2(h);
}

// native fp32 atomic add on global (no CAS loop)
__device__ __forceinline__ void fadd_native(float* p, float v) {
    unsafeAtomicAdd(p, v);
}

// pack two signed fixed-point deltas into one u64 operand; sign-extension of
// the low half makes sums decompose exactly: sum == (sum_hi<<32) + sum_lo.
__device__ __forceinline__ unsigned long long pack64(int hi, int lo) {
    return (unsigned long long)(((long long)hi << 32) + (long long)lo);
}

// direct global-atomic fallback for one (pixel, tile) when even the overflow
// list is full (requires out to be pre-zeroed; flush switches to += for the
// affected bin via the dirty flag)
__device__ void apply_fallback(float* imgw, float* onew, int n, int tr, int tc,
                               int ix, int iy, const float wx[2], const float wy[2],
                               float v0, float v1, float v2) {
#pragma unroll
    for (int dx = 0; dx < 2; ++dx) {
        int r = ix + dx;
        if ((unsigned)r >= (unsigned)HH || (r >> 5) != tr) continue;
#pragma unroll
        for (int dy = 0; dy < 2; ++dy) {
            int c = iy + dy;
            if ((unsigned)c >= (unsigned)WW || (c >> 5) != tc) continue;
            float w = wx[dx] * wy[dy];
            long o = (long)(n * CC) * HW + (long)r * WW + c;
            fadd_native(&imgw[o], v0 * w);
            fadd_native(&imgw[o + HW], v1 * w);
            fadd_native(&imgw[o + 2 * HW], v2 * w);
            fadd_native(&onew[o], w);
            fadd_native(&onew[o + HW], w);
            fadd_native(&onew[o + 2 * HW], w);
        }
    }
}

__global__ __launch_bounds__(256) void fwarp_binA(
    const float* __restrict__ img, const float* __restrict__ flo,
    float* __restrict__ imgw, float* __restrict__ onew,
    unsigned* __restrict__ cur, uint4* __restrict__ recs, int CAP,
    uint4* __restrict__ ov_rec, unsigned* __restrict__ ov_bin, int OCAP)
{
    __shared__ unsigned tbl[1024];    // per-(tr,tc): count, then base

    const int tid = threadIdx.x;
    const int idx = blockIdx.x * 256 + tid;   // over N*H*W
    const int wi = idx & (WW - 1);
    const int hi = (idx >> 10) & (HH - 1);
    const int n  = idx >> 20;                 // uniform per block

#pragma unroll
    for (int i = tid; i < 1024; i += 256) tbl[i] = 0u;

    const long pix = (long)hi * WW + wi;
    const long fb = (long)(n * 2) * HW + pix;
    const float yf = flo[fb];         // column shift
    const float xf = flo[fb + HW];    // row shift

    const float x1 = floorf(xf);
    const float y1 = floorf(yf);
    const float fx = xf - x1;
    const float fy = yf - y1;
    const int ix = (int)x1 + hi;      // target row (corner dx=0)
    const int iy = (int)y1 + wi;      // target col (corner dy=0)

    float wx[2], wy[2];
    wx[0] = __expf(-fx * fx);
    wx[1] = __expf(-(fx - 1.0f) * (fx - 1.0f));
    wy[0] = __expf(-fy * fy);
    wy[1] = __expf(-(fy - 1.0f) * (fy - 1.0f));

    const long ib = (long)(n * CC) * HW + pix;
    const float v0 = img[ib];
    const float v1 = img[ib + HW];
    const float v2 = img[ib + 2 * HW];

    // unique tile-rows touched by corner rows {ix, ix+1} ∩ [0,1024)
    int trs[2]; int ntr = 0;
    if ((unsigned)ix < (unsigned)HH) trs[ntr++] = ix >> 5;
    if ((unsigned)(ix + 1) < (unsigned)HH) {
        int t = (ix + 1) >> 5;
        if (ntr == 0 || t != trs[0]) trs[ntr++] = t;
    }
    int tcs[2]; int ntc = 0;
    if ((unsigned)iy < (unsigned)WW) tcs[ntc++] = iy >> 5;
    if ((unsigned)(iy + 1) < (unsigned)WW) {
        int t = (iy + 1) >> 5;
        if (ntc == 0 || t != tcs[0]) tcs[ntc++] = t;
    }

    const unsigned uwx = pack2h(wx[0], wx[1]);
    const unsigned uwy = pack2h(wy[0], wy[1]);
    const unsigned uv01 = pack2h(v0, v1);
    const unsigned uv2 = pack2h(v2, 0.0f) & 0xFFFFu;

    // collect this thread's (tile, loc) list: up to 4 records, distinct tiles
    int nrec = 0;
    int tv[4];
    unsigned locv[4];
#pragma unroll
    for (int i = 0; i < 2; ++i) {
        if (i >= ntr) break;
#pragma unroll
        for (int j = 0; j < 2; ++j) {
            if (j >= ntc) break;
            const int tr = trs[i], tc = tcs[j];
            const int lr = ix - (tr << 5);          // [-1..31]
            const int lc = iy - (tc << 5);          // [-1..31]
            tv[nrec] = (tr << 5) + tc;
            locv[nrec] = (unsigned)(lr + 1) | ((unsigned)(lc + 1) << 6);
            ++nrec;
        }
    }

    __syncthreads();   // tbl zeroed

    // phase 1: per-block count + per-record rank via LDS atomics
    unsigned rankv[4];
#pragma unroll
    for (int k = 0; k < 4; ++k)
        if (k < nrec) rankv[k] = atomicAdd(&tbl[tv[k]], 1u);
    __syncthreads();

    // phase 2: reserve global ranges — one atomic per distinct bin, issued
    // concurrently across lanes (4 independent atomics per thread, pipelined)
    unsigned cnts[4];
#pragma unroll
    for (int j = 0; j < 4; ++j) cnts[j] = tbl[tid + j * 256];
#pragma unroll
    for (int j = 0; j < 4; ++j) {
        if (cnts[j] > 0u) {
            const int e = tid + j * 256;
            const int bin = (n << 10) + e;
            tbl[e] = atomicAdd(&cur[(size_t)bin * CUR_STRIDE], cnts[j]);
        }
    }
    __syncthreads();

    // phase 3: store records at base + rank (consecutive per block per bin)
    uint4 rec;
    rec.x = uwx; rec.y = uwy; rec.z = uv01;
#pragma unroll
    for (int k = 0; k < 4; ++k) {
        if (k < nrec) {
            const unsigned slot = tbl[tv[k]] + rankv[k];
            const int bin = (n << 10) + tv[k];
            rec.w = uv2 | (locv[k] << 16);
            if (slot < (unsigned)CAP) {
                recs[(size_t)bin * CAP + slot] = rec;
            } else {
                const unsigned oslot = atomicAdd(&cur[OC_OFF], 1u);
                if ((int)oslot < OCAP) {
                    ov_rec[oslot] = rec;
                    ov_bin[oslot] = (unsigned)bin;
                } else {
                    // overflow list full: direct atomics + mark bin dirty
                    atomicOr(&cur[(size_t)bin * CUR_STRIDE + 1], 1u);
                    apply_fallback(imgw, onew, n, tv[k] >> 5, tv[k] & 31,
                                   ix, iy, wx, wy, v0, v1, v2);
                }
            }
        }
    }
}

__global__ __launch_bounds__(256, 8) void fwarp_binB(
    float* __restrict__ imgw, float* __restrict__ onew,
    const unsigned* __restrict__ cur, const uint4* __restrict__ recs, int CAP)
{
    // packed fixed-point accumulators: a01 = {p1|p0}, a2w = {pw|p2}
    __shared__ unsigned long long a01[1024];
    __shared__ unsigned long long a2w[1024];
    const int bin = blockIdx.x;
    const int tid = threadIdx.x;
    const int n = bin >> 10;
    const int tr = (bin >> 5) & 31;
    const int tc = bin & 31;

#pragma unroll
    for (int i = tid; i < 1024; i += 256) {
        a01[i] = 0ull; a2w[i] = 0ull;
    }
    __syncthreads();

    const int cnt = min((int)cur[(size_t)bin * CUR_STRIDE], CAP);
    const unsigned dirty = cur[(size_t)bin * CUR_STRIDE + 1];
    const uint4* base = recs + (size_t)bin * CAP;

    // batched record loads: RB independent 16B loads in flight per thread
    for (int i0 = tid; i0 < cnt; i0 += 256 * RB) {
        uint4 r[RB];
        bool m[RB];
#pragma unroll
        for (int b = 0; b < RB; ++b) {
            const int i = i0 + b * 256;
            m[b] = (i < cnt);
            if (m[b]) r[b] = base[i];
        }
#pragma unroll
        for (int b = 0; b < RB; ++b) {
            if (!m[b]) continue;
            const uint4 rec = r[b];
            const float2 wx = unpack2h(rec.x);
            const float2 wy = unpack2h(rec.y);
            const float2 v01 = unpack2h(rec.z);
            const float v2 = unpack2h(rec.w & 0xFFFFu).x;
            const unsigned loc = rec.w >> 16;
            const int lr = (int)(loc & 63u) - 1;        // [-1..31]
            const int lc = (int)(loc >> 6) - 1;
            const float wxv[2] = {wx.x, wx.y};
            const float wyv[2] = {wy.x, wy.y};
            const float v0s = v01.x * FPS;
            const float v1s = v01.y * FPS;
            const float v2s = v2 * FPS;
#pragma unroll
            for (int dx = 0; dx < 2; ++dx) {
                const int rr = lr + dx;
                if ((unsigned)rr >= 32u) continue;
#pragma unroll
                for (int dy = 0; dy < 2; ++dy) {
                    const int c = lc + dy;
                    if ((unsigned)c >= 32u) continue;
                    const float w = wxv[dx] * wyv[dy];
                    const int cell = (rr << 5) + c;
                    const int d0 = (int)(v0s * w);
                    const int d1 = (int)(v1s * w);
                    const int d2 = (int)(v2s * w);
                    const int dw = (int)(FPS * w);
                    atomicAdd(&a01[cell], pack64(d1, d0));
                    atomicAdd(&a2w[cell], pack64(dw, d2));
                }
            }
        }
    }
    __syncthreads();

    // flush: decode packed sums; bins tile the output exactly once -> plain
    // stores. (dirty bins — only possible when the overflow list overflowed —
    //  keep the += path on the pre-zeroed output.)
#pragma unroll
    for (int i = tid; i < 1024; i += 256) {
        const unsigned long long t01 = a01[i];
        const unsigned long long t2w = a2w[i];
        const int s0 = (int)(unsigned)t01;
        const int s1 = (int)((t01 - (unsigned long long)(long long)s0) >> 32);
        const int s2 = (int)(unsigned)t2w;
        const int sw = (int)((t2w - (unsigned long long)(long long)s2) >> 32);
        const float f0 = s0 * FPI;
        const float f1 = s1 * FPI;
        const float f2 = s2 * FPI;
        const float fw = sw * FPI;

        const int gr = (tr << 5) + (i >> 5);
        const int gc = (tc << 5) + (i & 31);
        const long o = (long)(n * CC) * HW + (long)gr * WW + gc;
        if (dirty == 0u) {
            imgw[o]          = f0;
            imgw[o + HW]     = f1;
            imgw[o + 2 * HW] = f2;
            onew[o]          = fw;
            onew[o + HW]     = fw;
            onew[o + 2 * HW] = fw;
        } else {
            imgw[o]          += f0;
            imgw[o + HW]     += f1;
            imgw[o + 2 * HW] += f2;
            onew[o]          += fw;
            onew[o + HW]     += fw;
            onew[o + 2 * HW] += fw;
        }
    }
}

// drains the overflow list (normally empty) after the flush
__global__ __launch_bounds__(256) void fwarp_binC(
    float* __restrict__ imgw, float* __restrict__ onew,
    const unsigned* __restrict__ cur,
    const uint4* __restrict__ ov_rec, const unsigned* __restrict__ ov_bin,
    int OCAP)
{
    const int ocnt = min((int)cur[OC_OFF], OCAP);
    for (int i = blockIdx.x * 256 + threadIdx.x; i < ocnt; i += gridDim.x * 256) {
        const uint4 rec = ov_rec[i];
        const int bin = (int)ov_bin[i];
        const int n = bin >> 10;
        const int tr = (bin >> 5) & 31;
        const int tc = bin & 31;
        const float2 wx = unpack2h(rec.x);
        const float2 wy = unpack2h(rec.y);
        const float2 v01 = unpack2h(rec.z);
        const float v2 = unpack2h(rec.w & 0xFFFFu).x;
        const unsigned loc = rec.w >> 16;
        const int lr = (int)(loc & 63u) - 1;
        const int lc = (int)(loc >> 6) - 1;
        const float wxv[2] = {wx.x, wx.y};
        const float wyv[2] = {wy.x, wy.y};
#pragma unroll
        for (int dx = 0; dx < 2; ++dx) {
            const int r = lr + dx;
            if ((unsigned)r >= 32u) continue;
#pragma unroll
            for (int dy = 0; dy < 2; ++dy) {
                const int c = lc + dy;
                if ((unsigned)c >= 32u) continue;
                const float w = wxv[dx] * wyv[dy];
                const int gr = (tr << 5) + r;
                const int gc = (tc << 5) + c;
                const long o = (long)(n * CC) * HW + (long)gr * WW + gc;
                fadd_native(&imgw[o], v01.x * w);
                fadd_native(&imgw[o + HW], v01.y * w);
                fadd_native(&imgw[o + 2 * HW], v2 * w);
                fadd_native(&onew[o], w);
                fadd_native(&onew[o + HW], w);
                fadd_native(&onew[o + 2 * HW], w);
            }
        }
    }
}

extern "C" void kernel_launch(void* const* d_in, const int* in_sizes, int n_in,
                              void* d_out, int out_size, void* d_ws, size_t ws_size,
                              hipStream_t stream) {
    const float* img = (const float*)d_in[0];
    const float* flo = (const float*)d_in[1];
    float* imgw = (float*)d_out;
    float* onew = imgw + (long)NCHW;

    unsigned* cur = (unsigned*)d_ws;

    size_t avail = ws_size > (size_t)CUR_BYTES ? ws_size - CUR_BYTES : 0;
    // 85% of remaining workspace to bins (CAP ~2x mean load of 1090), 15% to
    // the overflow list
    long cap_l = (long)((avail / 20 * 17) / ((size_t)NBINS * 16));
    int CAP = (int)(cap_l > 2048 ? 2048 : (cap_l < 0 ? 0 : cap_l));
    size_t recs_bytes = (size_t)NBINS * 16 * CAP;
    size_t ov_bytes = avail - recs_bytes;
    long ocap_l = (long)(ov_bytes / 20);
    int OCAP = (int)(ocap_l > (1L << 22) ? (1L << 22) : (ocap_l < 0 ? 0 : ocap_l));

    uint4* recs = (uint4*)((char*)d_ws + CUR_BYTES);
    uint4* ov_rec = (uint4*)((char*)recs + recs_bytes);
    unsigned* ov_bin = (unsigned*)((char*)ov_rec + (size_t)OCAP * 16);

    hipMemsetAsync(d_out, 0, (size_t)out_size * sizeof(float), stream);
    hipMemsetAsync(cur, 0, CUR_BYTES, stream);

    const int total = NN * HH * WW;            // 8388608
    fwarp_binA<<<total / 256, 256, 0, stream>>>(img, flo, imgw, onew, cur, recs,
                                                CAP, ov_rec, ov_bin, OCAP);
    fwarp_binB<<<NBINS, 256, 0, stream>>>(imgw, onew, cur, recs, CAP);
    fwarp_binC<<<64, 256, 0, stream>>>(imgw, onew, cur, ov_rec, ov_bin, OCAP);
}

// Round 7
// 423.335 us; speedup vs baseline: 2.4535x; 1.0677x over previous
//
#include <hip/hip_runtime.h>
#include <hip/hip_fp16.h>

// ForwardWarp via two-phase binning:
//   Pass A: per source pixel, emit 16B record(s) into per-output-tile bins.
//           Block-aggregated slot allocation (LDS count table + one global
//           atomicAdd per distinct bin per block). Overflow records append
//           to a global overflow list (pass C drains it after the flush).
//   Pass B: per tile, batched record loads, LDS accumulate via PACKED u64
//           fixed-point atomics: 2 planes per ds_add_u64 (native integer
//           LDS atomics; fp32 LDS atomicAdd — even unsafeAtomicAdd — lowers
//           to a ~190cy CAS loop on gfx950), exact sums decoded at flush.
//   Pass C: drains the overflow list with global atomics (normally empty).
// img: (8,3,1024,1024) fp32; flo: (8,2,1024,1024) fp32
// d_out = [imgw (8,3,1024,1024) | onew (8,3,1024,1024)] fp32 (out_size BYTES).

#define NN 8
#define CC 3
#define HH 1024
#define WW 1024
#define HW (HH * WW)
#define NCHW (NN * CC * HW)
#define NBINS (NN * 32 * 32)          // 8192 tiles of 32x32
#define CUR_STRIDE 32                 // 1 counter per 128B line (kills false sharing)
#define OC_OFF (NBINS * CUR_STRIDE)   // overflow-list counter slot
#define CUR_BYTES ((NBINS * CUR_STRIDE + 32) * 4)
#define RB 4                          // record-load batch depth in pass B

#define FPS 65536.0f                  // fixed-point scale 16.16
#define FPI (1.0f / 65536.0f)

__device__ __forceinline__ unsigned pack2h(float a, float b) {
    __half2 h = __floats2half2_rn(a, b);
    return *reinterpret_cast<unsigned*>(&h);
}
__device__ __forceinline__ float2 unpack2h(unsigned u) {
    __half2 h = *reinterpret_cast<__half2*>(&u);
    return __half22float2(h);
}

// native fp32 atomic add on global (no CAS loop)
__device__ __forceinline__ void fadd_native(float* p, float v) {
    unsafeAtomicAdd(p, v);
}

// pack two signed fixed-point deltas into one u64 operand; sign-extension of
// the low half makes sums decompose exactly: sum == (sum_hi<<32) + sum_lo.
__device__ __forceinline__ unsigned long long pack64(int hi, int lo) {
    return (unsigned long long)(((long long)hi << 32) + (long long)lo);
}

// direct global-atomic fallback for one (pixel, tile) when even the overflow
// list is full (requires out to be pre-zeroed; flush switches to += for the
// affected bin via the dirty flag)
__device__ void apply_fallback(float* imgw, float* onew, int n, int tr, int tc,
                               int ix, int iy, const float wx[2], const float wy[2],
                               float v0, float v1, float v2) {
#pragma unroll
    for (int dx = 0; dx < 2; ++dx) {
        int r = ix + dx;
        if ((unsigned)r >= (unsigned)HH || (r >> 5) != tr) continue;
#pragma unroll
        for (int dy = 0; dy < 2; ++dy) {
            int c = iy + dy;
            if ((unsigned)c >= (unsigned)WW || (c >> 5) != tc) continue;
            float w = wx[dx] * wy[dy];
            long o = (long)(n * CC) * HW + (long)r * WW + c;
            fadd_native(&imgw[o], v0 * w);
            fadd_native(&imgw[o + HW], v1 * w);
            fadd_native(&imgw[o + 2 * HW], v2 * w);
            fadd_native(&onew[o], w);
            fadd_native(&onew[o + HW], w);
            fadd_native(&onew[o + 2 * HW], w);
        }
    }
}

__global__ __launch_bounds__(256) void fwarp_binA(
    const float* __restrict__ img, const float* __restrict__ flo,
    float* __restrict__ imgw, float* __restrict__ onew,
    unsigned* __restrict__ cur, uint4* __restrict__ recs, int CAP,
    uint4* __restrict__ ov_rec, unsigned* __restrict__ ov_bin, int OCAP)
{
    __shared__ unsigned tbl[1024];    // per-(tr,tc): count, then base

    const int tid = threadIdx.x;
    const int idx = blockIdx.x * 256 + tid;   // over N*H*W
    const int wi = idx & (WW - 1);
    const int hi = (idx >> 10) & (HH - 1);
    const int n  = idx >> 20;                 // uniform per block

#pragma unroll
    for (int i = tid; i < 1024; i += 256) tbl[i] = 0u;

    const long pix = (long)hi * WW + wi;
    const long fb = (long)(n * 2) * HW + pix;
    const float yf = flo[fb];         // column shift
    const float xf = flo[fb + HW];    // row shift

    const float x1 = floorf(xf);
    const float y1 = floorf(yf);
    const float fx = xf - x1;
    const float fy = yf - y1;
    const int ix = (int)x1 + hi;      // target row (corner dx=0)
    const int iy = (int)y1 + wi;      // target col (corner dy=0)

    float wx[2], wy[2];
    wx[0] = __expf(-fx * fx);
    wx[1] = __expf(-(fx - 1.0f) * (fx - 1.0f));
    wy[0] = __expf(-fy * fy);
    wy[1] = __expf(-(fy - 1.0f) * (fy - 1.0f));

    const long ib = (long)(n * CC) * HW + pix;
    const float v0 = img[ib];
    const float v1 = img[ib + HW];
    const float v2 = img[ib + 2 * HW];

    // unique tile-rows touched by corner rows {ix, ix+1} ∩ [0,1024)
    int trs[2]; int ntr = 0;
    if ((unsigned)ix < (unsigned)HH) trs[ntr++] = ix >> 5;
    if ((unsigned)(ix + 1) < (unsigned)HH) {
        int t = (ix + 1) >> 5;
        if (ntr == 0 || t != trs[0]) trs[ntr++] = t;
    }
    int tcs[2]; int ntc = 0;
    if ((unsigned)iy < (unsigned)WW) tcs[ntc++] = iy >> 5;
    if ((unsigned)(iy + 1) < (unsigned)WW) {
        int t = (iy + 1) >> 5;
        if (ntc == 0 || t != tcs[0]) tcs[ntc++] = t;
    }

    const unsigned uwx = pack2h(wx[0], wx[1]);
    const unsigned uwy = pack2h(wy[0], wy[1]);
    const unsigned uv01 = pack2h(v0, v1);
    const unsigned uv2 = pack2h(v2, 0.0f) & 0xFFFFu;

    // collect this thread's (tile, loc) list: up to 4 records, distinct tiles
    int nrec = 0;
    int tv[4];
    unsigned locv[4];
#pragma unroll
    for (int i = 0; i < 2; ++i) {
        if (i >= ntr) break;
#pragma unroll
        for (int j = 0; j < 2; ++j) {
            if (j >= ntc) break;
            const int tr = trs[i], tc = tcs[j];
            const int lr = ix - (tr << 5);          // [-1..31]
            const int lc = iy - (tc << 5);          // [-1..31]
            tv[nrec] = (tr << 5) + tc;
            locv[nrec] = (unsigned)(lr + 1) | ((unsigned)(lc + 1) << 6);
            ++nrec;
        }
    }

    __syncthreads();   // tbl zeroed

    // phase 1: per-block count + per-record rank via LDS atomics
    unsigned rankv[4];
#pragma unroll
    for (int k = 0; k < 4; ++k)
        if (k < nrec) rankv[k] = atomicAdd(&tbl[tv[k]], 1u);
    __syncthreads();

    // phase 2: reserve global ranges — one atomic per distinct bin, issued
    // concurrently across lanes (4 independent atomics per thread, pipelined)
    unsigned cnts[4];
#pragma unroll
    for (int j = 0; j < 4; ++j) cnts[j] = tbl[tid + j * 256];
#pragma unroll
    for (int j = 0; j < 4; ++j) {
        if (cnts[j] > 0u) {
            const int e = tid + j * 256;
            const int bin = (n << 10) + e;
            tbl[e] = atomicAdd(&cur[(size_t)bin * CUR_STRIDE], cnts[j]);
        }
    }
    __syncthreads();

    // phase 3: store records at base + rank (consecutive per block per bin)
    uint4 rec;
    rec.x = uwx; rec.y = uwy; rec.z = uv01;
#pragma unroll
    for (int k = 0; k < 4; ++k) {
        if (k < nrec) {
            const unsigned slot = tbl[tv[k]] + rankv[k];
            const int bin = (n << 10) + tv[k];
            rec.w = uv2 | (locv[k] << 16);
            if (slot < (unsigned)CAP) {
                recs[(size_t)bin * CAP + slot] = rec;
            } else {
                const unsigned oslot = atomicAdd(&cur[OC_OFF], 1u);
                if ((int)oslot < OCAP) {
                    ov_rec[oslot] = rec;
                    ov_bin[oslot] = (unsigned)bin;
                } else {
                    // overflow list full: direct atomics + mark bin dirty
                    atomicOr(&cur[(size_t)bin * CUR_STRIDE + 1], 1u);
                    apply_fallback(imgw, onew, n, tv[k] >> 5, tv[k] & 31,
                                   ix, iy, wx, wy, v0, v1, v2);
                }
            }
        }
    }
}

__global__ __launch_bounds__(256, 8) void fwarp_binB(
    float* __restrict__ imgw, float* __restrict__ onew,
    const unsigned* __restrict__ cur, const uint4* __restrict__ recs, int CAP)
{
    // packed fixed-point accumulators: a01 = {p1|p0}, a2w = {pw|p2}
    __shared__ unsigned long long a01[1024];
    __shared__ unsigned long long a2w[1024];
    const int bin = blockIdx.x;
    const int tid = threadIdx.x;
    const int n = bin >> 10;
    const int tr = (bin >> 5) & 31;
    const int tc = bin & 31;

#pragma unroll
    for (int i = tid; i < 1024; i += 256) {
        a01[i] = 0ull; a2w[i] = 0ull;
    }
    __syncthreads();

    const int cnt = min((int)cur[(size_t)bin * CUR_STRIDE], CAP);
    const unsigned dirty = cur[(size_t)bin * CUR_STRIDE + 1];
    const uint4* base = recs + (size_t)bin * CAP;

    // batched record loads: RB independent 16B loads in flight per thread
    for (int i0 = tid; i0 < cnt; i0 += 256 * RB) {
        uint4 r[RB];
        bool m[RB];
#pragma unroll
        for (int b = 0; b < RB; ++b) {
            const int i = i0 + b * 256;
            m[b] = (i < cnt);
            if (m[b]) r[b] = base[i];
        }
#pragma unroll
        for (int b = 0; b < RB; ++b) {
            if (!m[b]) continue;
            const uint4 rec = r[b];
            const float2 wx = unpack2h(rec.x);
            const float2 wy = unpack2h(rec.y);
            const float2 v01 = unpack2h(rec.z);
            const float v2 = unpack2h(rec.w & 0xFFFFu).x;
            const unsigned loc = rec.w >> 16;
            const int lr = (int)(loc & 63u) - 1;        // [-1..31]
            const int lc = (int)(loc >> 6) - 1;
            const float wxv[2] = {wx.x, wx.y};
            const float wyv[2] = {wy.x, wy.y};
            const float v0s = v01.x * FPS;
            const float v1s = v01.y * FPS;
            const float v2s = v2 * FPS;
#pragma unroll
            for (int dx = 0; dx < 2; ++dx) {
                const int rr = lr + dx;
                if ((unsigned)rr >= 32u) continue;
#pragma unroll
                for (int dy = 0; dy < 2; ++dy) {
                    const int c = lc + dy;
                    if ((unsigned)c >= 32u) continue;
                    const float w = wxv[dx] * wyv[dy];
                    const int cell = (rr << 5) + c;
                    const int d0 = (int)(v0s * w);
                    const int d1 = (int)(v1s * w);
                    const int d2 = (int)(v2s * w);
                    const int dw = (int)(FPS * w);
                    atomicAdd(&a01[cell], pack64(d1, d0));
                    atomicAdd(&a2w[cell], pack64(dw, d2));
                }
            }
        }
    }
    __syncthreads();

    // flush: decode packed sums; bins tile the output exactly once -> plain
    // stores. (dirty bins — only possible when the overflow list overflowed —
    //  keep the += path on the pre-zeroed output.)
#pragma unroll
    for (int i = tid; i < 1024; i += 256) {
        const unsigned long long t01 = a01[i];
        const unsigned long long t2w = a2w[i];
        const int s0 = (int)(unsigned)t01;
        const int s1 = (int)((t01 - (unsigned long long)(long long)s0) >> 32);
        const int s2 = (int)(unsigned)t2w;
        const int sw = (int)((t2w - (unsigned long long)(long long)s2) >> 32);
        const float f0 = s0 * FPI;
        const float f1 = s1 * FPI;
        const float f2 = s2 * FPI;
        const float fw = sw * FPI;

        const int gr = (tr << 5) + (i >> 5);
        const int gc = (tc << 5) + (i & 31);
        const long o = (long)(n * CC) * HW + (long)gr * WW + gc;
        if (dirty == 0u) {
            imgw[o]          = f0;
            imgw[o + HW]     = f1;
            imgw[o + 2 * HW] = f2;
            onew[o]          = fw;
            onew[o + HW]     = fw;
            onew[o + 2 * HW] = fw;
        } else {
            imgw[o]          += f0;
            imgw[o + HW]     += f1;
            imgw[o + 2 * HW] += f2;
            onew[o]          += fw;
            onew[o + HW]     += fw;
            onew[o + 2 * HW] += fw;
        }
    }
}

// drains the overflow list (normally empty) after the flush
__global__ __launch_bounds__(256) void fwarp_binC(
    float* __restrict__ imgw, float* __restrict__ onew,
    const unsigned* __restrict__ cur,
    const uint4* __restrict__ ov_rec, const unsigned* __restrict__ ov_bin,
    int OCAP)
{
    const int ocnt = min((int)cur[OC_OFF], OCAP);
    for (int i = blockIdx.x * 256 + threadIdx.x; i < ocnt; i += gridDim.x * 256) {
        const uint4 rec = ov_rec[i];
        const int bin = (int)ov_bin[i];
        const int n = bin >> 10;
        const int tr = (bin >> 5) & 31;
        const int tc = bin & 31;
        const float2 wx = unpack2h(rec.x);
        const float2 wy = unpack2h(rec.y);
        const float2 v01 = unpack2h(rec.z);
        const float v2 = unpack2h(rec.w & 0xFFFFu).x;
        const unsigned loc = rec.w >> 16;
        const int lr = (int)(loc & 63u) - 1;
        const int lc = (int)(loc >> 6) - 1;
        const float wxv[2] = {wx.x, wx.y};
        const float wyv[2] = {wy.x, wy.y};
#pragma unroll
        for (int dx = 0; dx < 2; ++dx) {
            const int r = lr + dx;
            if ((unsigned)r >= 32u) continue;
#pragma unroll
            for (int dy = 0; dy < 2; ++dy) {
                const int c = lc + dy;
                if ((unsigned)c >= 32u) continue;
                const float w = wxv[dx] * wyv[dy];
                const int gr = (tr << 5) + r;
                const int gc = (tc << 5) + c;
                const long o = (long)(n * CC) * HW + (long)gr * WW + gc;
                fadd_native(&imgw[o], v01.x * w);
                fadd_native(&imgw[o + HW], v01.y * w);
                fadd_native(&imgw[o + 2 * HW], v2 * w);
                fadd_native(&onew[o], w);
                fadd_native(&onew[o + HW], w);
                fadd_native(&onew[o + 2 * HW], w);
            }
        }
    }
}

extern "C" void kernel_launch(void* const* d_in, const int* in_sizes, int n_in,
                              void* d_out, int out_size, void* d_ws, size_t ws_size,
                              hipStream_t stream) {
    const float* img = (const float*)d_in[0];
    const float* flo = (const float*)d_in[1];
    float* imgw = (float*)d_out;
    float* onew = imgw + (long)NCHW;

    unsigned* cur = (unsigned*)d_ws;

    size_t avail = ws_size > (size_t)CUR_BYTES ? ws_size - CUR_BYTES : 0;
    // 85% of remaining workspace to bins (CAP ~2x mean load of 1090), 15% to
    // the overflow list
    long cap_l = (long)((avail / 20 * 17) / ((size_t)NBINS * 16));
    int CAP = (int)(cap_l > 2048 ? 2048 : (cap_l < 0 ? 0 : cap_l));
    size_t recs_bytes = (size_t)NBINS * 16 * CAP;
    size_t ov_bytes = avail - recs_bytes;
    long ocap_l = (long)(ov_bytes / 20);
    int OCAP = (int)(ocap_l > (1L << 22) ? (1L << 22) : (ocap_l < 0 ? 0 : ocap_l));

    uint4* recs = (uint4*)((char*)d_ws + CUR_BYTES);
    uint4* ov_rec = (uint4*)((char*)recs + recs_bytes);
    unsigned* ov_bin = (unsigned*)((char*)ov_rec + (size_t)OCAP * 16);

    // out_size is in BYTES (measured: fill WRITE_SIZE was exactly 4x the
    // 201MB output when multiplied by sizeof(float) — R6 counter evidence)
    hipMemsetAsync(d_out, 0, (size_t)out_size, stream);
    hipMemsetAsync(cur, 0, CUR_BYTES, stream);

    const int total = NN * HH * WW;            // 8388608
    fwarp_binA<<<total / 256, 256, 0, stream>>>(img, flo, imgw, onew, cur, recs,
                                                CAP, ov_rec, ov_bin, OCAP);
    fwarp_binB<<<NBINS, 256, 0, stream>>>(imgw, onew, cur, recs, CAP);
    fwarp_binC<<<64, 256, 0, stream>>>(imgw, onew, cur, ov_rec, ov_bin, OCAP);
}